// Round 1
// baseline (1524.475 us; speedup 1.0000x reference)
//
#include <hip/hip_runtime.h>
#include <hip/hip_bf16.h>
#include <math.h>

// ResGatedGraphConv x3 + logit head for MI355X.
// Strategy: build CSR by dst once (no float atomics), then per layer:
//   nodelin (k,q) + nodelin (v, skip-base) + edge gather/gate/aggregate kernel.

#define D_CH 64
#define E_CH 16

__device__ __forceinline__ float bcastf(float v, int srclane) {
  return __int_as_float(__builtin_amdgcn_readlane(__float_as_int(v), srclane));
}

// ---- K0: detect whether edge_index is int64 (odd 32-bit words all zero) ----
__global__ void k_detect(const unsigned int* __restrict__ ei, int* __restrict__ flag,
                         int n_samples) {
  __shared__ unsigned int red[256];
  unsigned int acc = 0;
  for (int i = threadIdx.x; i < n_samples; i += 256) acc |= ei[2 * i + 1];
  red[threadIdx.x] = acc;
  __syncthreads();
  for (int s = 128; s > 0; s >>= 1) {
    if (threadIdx.x < s) red[threadIdx.x] |= red[threadIdx.x + s];
    __syncthreads();
  }
  if (threadIdx.x == 0) flag[0] = (red[0] == 0u) ? 1 : 0;
}

// ---- K1: normalize edge_index into int32 src[], dst[] ----
__global__ void k_normalize(const void* __restrict__ ei, const int* __restrict__ flag,
                            int* __restrict__ src, int* __restrict__ dst, int E) {
  int e = blockIdx.x * blockDim.x + threadIdx.x;
  if (e >= E) return;
  if (flag[0]) {
    const long long* p = (const long long*)ei;
    src[e] = (int)p[e];
    dst[e] = (int)p[E + e];
  } else {
    const int* p = (const int*)ei;
    src[e] = p[e];
    dst[e] = p[E + e];
  }
}

__global__ void k_zero(int* __restrict__ p, int n) {
  int i = blockIdx.x * blockDim.x + threadIdx.x;
  if (i < n) p[i] = 0;
}

__global__ void k_hist(const int* __restrict__ dst, int* __restrict__ deg, int E) {
  int e = blockIdx.x * blockDim.x + threadIdx.x;
  if (e < E) atomicAdd(&deg[dst[e]], 1);
}

// ---- exclusive scan of degrees -> offsets; also re-init cursor=offsets ----
__global__ void k_scan(int* __restrict__ deg_cursor, int* __restrict__ offsets, int N) {
  __shared__ int buf[1024];
  __shared__ int carry;
  if (threadIdx.x == 0) carry = 0;
  __syncthreads();
  for (int base = 0; base < N; base += 1024) {
    int i = base + threadIdx.x;
    int val = (i < N) ? deg_cursor[i] : 0;
    buf[threadIdx.x] = val;
    __syncthreads();
    for (int off = 1; off < 1024; off <<= 1) {
      int t = (threadIdx.x >= off) ? buf[threadIdx.x - off] : 0;
      __syncthreads();
      buf[threadIdx.x] += t;
      __syncthreads();
    }
    int excl = buf[threadIdx.x] - val;
    int c = carry;
    int tot = buf[1023];
    __syncthreads();
    if (i < N) {
      offsets[i] = c + excl;
      deg_cursor[i] = c + excl;  // cursor for scatter
    }
    if (threadIdx.x == 0) carry = c + tot;
    __syncthreads();
  }
  if (threadIdx.x == 0) offsets[N] = carry;
}

__global__ void k_scatter(const int* __restrict__ src, const int* __restrict__ dst,
                          int* __restrict__ cursor, int* __restrict__ csr_src,
                          int* __restrict__ csr_eid, int E) {
  int e = blockIdx.x * blockDim.x + threadIdx.x;
  if (e >= E) return;
  int d = dst[e];
  int p = atomicAdd(&cursor[d], 1);
  csr_src[p] = src[e];
  csr_eid[p] = e;
}

// ---- node linear: outa = hin@Wa + ba ; outb = hin@Wb + bb ----
// One wave per node (grid-stride). Lane d holds weight columns Wa[:,d], Wb[:,d]
// in registers (fully unrolled -> static indices). h[c] broadcast via readlane.
__global__ __launch_bounds__(256, 1) void k_nodelin(
    const float* __restrict__ hin, const float* __restrict__ Wa,
    const float* __restrict__ ba, const float* __restrict__ Wb,
    const float* __restrict__ bb, float* __restrict__ outa, float* __restrict__ outb,
    int N) {
  int lane = threadIdx.x & 63;
  int wave = blockIdx.x * (blockDim.x >> 6) + (threadIdx.x >> 6);
  int nwaves = gridDim.x * (blockDim.x >> 6);
  float wa[64], wb[64];
#pragma unroll
  for (int c = 0; c < 64; ++c) {
    wa[c] = Wa[c * 64 + lane];
    wb[c] = Wb[c * 64 + lane];
  }
  float bav = ba[lane], bbv = bb[lane];
  for (int i = wave; i < N; i += nwaves) {
    float h = hin[(size_t)i * 64 + lane];
    float a = bav, b = bbv;
#pragma unroll
    for (int c = 0; c < 64; ++c) {
      float hc = bcastf(h, c);
      a = fmaf(hc, wa[c], a);
      b = fmaf(hc, wb[c], b);
    }
    outa[(size_t)i * 64 + lane] = a;
    outb[(size_t)i * 64 + lane] = b;
  }
}

// ---- edge gather + gate + aggregate + skip + elu (+ output fusion) ----
// MODE 0: write hnext only. MODE 1: write feat (ws) + d_out feat block + concat cols.
// MODE 2: fuse logits GEMV + sigmoid; write d_out[0:N] and concat col 64.
template <int MODE>
__global__ __launch_bounds__(256, 4) void k_edge(
    const int* __restrict__ offsets, const int* __restrict__ csr_src,
    const int* __restrict__ csr_eid, const float* __restrict__ kk,
    const float* __restrict__ qq, const float* __restrict__ vv,
    const float* __restrict__ base, const float* __restrict__ ea,
    const float* __restrict__ We, const float* __restrict__ be,
    float* __restrict__ hnext, float* __restrict__ dout,
    const float* __restrict__ Wl, const float* __restrict__ bl, int N) {
  int lane = threadIdx.x & 63;
  int wave = blockIdx.x * (blockDim.x >> 6) + (threadIdx.x >> 6);
  int nwaves = gridDim.x * (blockDim.x >> 6);
  float we[16];
#pragma unroll
  for (int c = 0; c < 16; ++c) we[c] = We[c * 64 + lane];
  float bev = be[lane];
  float wl = (MODE == 2) ? Wl[lane] : 0.f;
  float bl0 = (MODE == 2) ? bl[0] : 0.f;
  for (int i = wave; i < N; i += nwaves) {
    float ki = kk[(size_t)i * 64 + lane] + bev;  // fold be into k_i
    float acc = base[(size_t)i * 64 + lane];
    int p0 = __builtin_amdgcn_readfirstlane(offsets[i]);
    int p1 = __builtin_amdgcn_readfirstlane(offsets[i + 1]);
    for (int p = p0; p < p1; ++p) {
      int j = __builtin_amdgcn_readfirstlane(csr_src[p]);
      int eid = __builtin_amdgcn_readfirstlane(csr_eid[p]);
      const float4* eaq = (const float4*)(ea + (size_t)eid * E_CH);
      float4 e0 = eaq[0], e1 = eaq[1], e2 = eaq[2], e3 = eaq[3];
      float ev = 0.f;
      ev = fmaf(e0.x, we[0], ev);  ev = fmaf(e0.y, we[1], ev);
      ev = fmaf(e0.z, we[2], ev);  ev = fmaf(e0.w, we[3], ev);
      ev = fmaf(e1.x, we[4], ev);  ev = fmaf(e1.y, we[5], ev);
      ev = fmaf(e1.z, we[6], ev);  ev = fmaf(e1.w, we[7], ev);
      ev = fmaf(e2.x, we[8], ev);  ev = fmaf(e2.y, we[9], ev);
      ev = fmaf(e2.z, we[10], ev); ev = fmaf(e2.w, we[11], ev);
      ev = fmaf(e3.x, we[12], ev); ev = fmaf(e3.y, we[13], ev);
      ev = fmaf(e3.z, we[14], ev); ev = fmaf(e3.w, we[15], ev);
      float qj = qq[(size_t)j * 64 + lane];
      float vj = vv[(size_t)j * 64 + lane];
      float g = ki + qj + ev;
      g = 1.0f / (1.0f + __expf(-g));
      acc = fmaf(g, vj, acc);
    }
    float r = (acc > 0.f) ? acc : expm1f(acc);  // elu
    if (MODE == 0) {
      hnext[(size_t)i * 64 + lane] = r;
    } else if (MODE == 1) {
      hnext[(size_t)i * 64 + lane] = r;
      dout[(size_t)N + (size_t)i * 64 + lane] = r;            // feat block
      dout[(size_t)N * 65 + (size_t)i * 65 + lane] = r;       // concat block
    } else {
      float dot = r * wl;
#pragma unroll
      for (int m = 32; m >= 1; m >>= 1) dot += __shfl_xor(dot, m);
      float logit = dot + bl0;
      if (lane == 0) {
        dout[i] = 1.0f / (1.0f + __expf(-logit));
        dout[(size_t)N * 65 + (size_t)i * 65 + 64] = logit;   // raw logit col
      }
    }
  }
}

extern "C" void kernel_launch(void* const* d_in, const int* in_sizes, int n_in,
                              void* d_out, int out_size, void* d_ws, size_t ws_size,
                              hipStream_t stream) {
  const float* x   = (const float*)d_in[0];
  const void*  ei  = d_in[1];
  const float* ea  = (const float*)d_in[2];
  const float* Wk  = (const float*)d_in[3];
  const float* bk  = (const float*)d_in[4];
  const float* Wq  = (const float*)d_in[5];
  const float* bq  = (const float*)d_in[6];
  const float* Wv  = (const float*)d_in[7];
  const float* bv  = (const float*)d_in[8];
  const float* We  = (const float*)d_in[9];
  const float* be  = (const float*)d_in[10];
  const float* Ws  = (const float*)d_in[11];
  const float* bia = (const float*)d_in[12];
  const float* Wl  = (const float*)d_in[13];
  const float* bl  = (const float*)d_in[14];
  int N = in_sizes[0] / D_CH;
  int E = in_sizes[2] / E_CH;

  char* w = (char*)d_ws;
  auto alloc = [&](size_t bytes) -> char* {
    char* r = w;
    w += (bytes + 255) & ~(size_t)255;
    return r;
  };
  int* flag     = (int*)alloc(16);
  int* src      = (int*)alloc((size_t)E * 4);
  int* dstA     = (int*)alloc((size_t)E * 4);
  int* offsets  = (int*)alloc((size_t)(N + 1) * 4);
  int* cursor   = (int*)alloc((size_t)N * 4);
  int* csr_src  = (int*)alloc((size_t)E * 4);
  int* csr_eid  = (int*)alloc((size_t)E * 4);
  float* kk     = (float*)alloc((size_t)N * D_CH * 4);
  float* qqb    = (float*)alloc((size_t)N * D_CH * 4);
  float* vvb    = (float*)alloc((size_t)N * D_CH * 4);
  float* baseb  = (float*)alloc((size_t)N * D_CH * 4);
  float* h1     = (float*)alloc((size_t)N * D_CH * 4);
  float* feat   = (float*)alloc((size_t)N * D_CH * 4);
  float* dout   = (float*)d_out;

  int gE = (E + 255) / 256;
  int gN = (N + 255) / 256;

  k_detect<<<1, 256, 0, stream>>>((const unsigned int*)ei, flag, 8192);
  k_normalize<<<gE, 256, 0, stream>>>(ei, flag, src, dstA, E);
  k_zero<<<gN, 256, 0, stream>>>(cursor, N);
  k_hist<<<gE, 256, 0, stream>>>(dstA, cursor, E);
  k_scan<<<1, 1024, 0, stream>>>(cursor, offsets, N);
  k_scatter<<<gE, 256, 0, stream>>>(src, dstA, cursor, csr_src, csr_eid, E);

  const float* hin = x;
  for (int l = 0; l < 3; ++l) {
    const float* Wk_l = Wk + (size_t)l * 4096;
    const float* bk_l = bk + (size_t)l * 64;
    const float* Wq_l = Wq + (size_t)l * 4096;
    const float* bq_l = bq + (size_t)l * 64;
    const float* Wv_l = Wv + (size_t)l * 4096;
    const float* bv_l = bv + (size_t)l * 64;
    const float* We_l = We + (size_t)l * 1024;
    const float* be_l = be + (size_t)l * 64;
    const float* Ws_l = Ws + (size_t)l * 4096;
    const float* bi_l = bia + (size_t)l * 64;

    k_nodelin<<<1024, 256, 0, stream>>>(hin, Wk_l, bk_l, Wq_l, bq_l, kk, qqb, N);
    k_nodelin<<<1024, 256, 0, stream>>>(hin, Wv_l, bv_l, Ws_l, bi_l, vvb, baseb, N);
    if (l == 0) {
      k_edge<0><<<2048, 256, 0, stream>>>(offsets, csr_src, csr_eid, kk, qqb, vvb,
                                          baseb, ea, We_l, be_l, h1, dout, Wl, bl, N);
      hin = h1;
    } else if (l == 1) {
      k_edge<1><<<2048, 256, 0, stream>>>(offsets, csr_src, csr_eid, kk, qqb, vvb,
                                          baseb, ea, We_l, be_l, feat, dout, Wl, bl, N);
      hin = feat;
    } else {
      k_edge<2><<<2048, 256, 0, stream>>>(offsets, csr_src, csr_eid, kk, qqb, vvb,
                                          baseb, ea, We_l, be_l, h1, dout, Wl, bl, N);
    }
  }
}

// Round 9
// 1269.553 us; speedup vs baseline: 1.2008x; 1.2008x over previous
//
#include <hip/hip_runtime.h>
#include <hip/hip_bf16.h>
#include <math.h>

// ResGatedGraphConv x3 + logit head for MI355X.
// R8 (resubmit — infra failures R4-R8; kernel unmeasured): coalesced CSR
// meta + readlane bcast + 4-edge pipeline, q/v interleaved, parallel
// 3-kernel scan, fused prep kernels.

#define D_CH 64
#define E_CH 16

// ---- prep: zero degree array; block 0 also detects int64 vs int32 ----
__global__ void k_prep(const unsigned int* __restrict__ ei, int* __restrict__ flag,
                       int* __restrict__ deg, int N, int nsamp) {
  int i = blockIdx.x * blockDim.x + threadIdx.x;
  if (i < N) deg[i] = 0;
  if (blockIdx.x == 0) {
    unsigned int acc = 0;
    for (int s = threadIdx.x; s < nsamp; s += blockDim.x) acc |= ei[2 * s + 1];
    int nz = __syncthreads_or(acc != 0u);
    if (threadIdx.x == 0) flag[0] = nz ? 0 : 1;
  }
}

// ---- normalize edge_index + histogram degrees (fused) ----
__global__ void k_normhist(const void* __restrict__ ei, const int* __restrict__ flag,
                           int* __restrict__ src, int* __restrict__ dstA,
                           int* __restrict__ deg, int E) {
  int e = blockIdx.x * blockDim.x + threadIdx.x;
  if (e >= E) return;
  int s, d;
  if (flag[0]) {
    const long long* p = (const long long*)ei;
    s = (int)p[e];
    d = (int)p[E + e];
  } else {
    const int* p = (const int*)ei;
    s = p[e];
    d = p[E + e];
  }
  src[e] = s;
  dstA[e] = d;
  atomicAdd(&deg[d], 1);
}

// ---- scan part 1: per-1024-chunk sums ----
__global__ void k_scanpart(const int* __restrict__ deg, int* __restrict__ partial, int N) {
  __shared__ int wsum[4];
  int tid = threadIdx.x, lane = tid & 63, w = tid >> 6;
  int i0 = blockIdx.x * 1024 + tid * 4;
  int4 v = make_int4(0, 0, 0, 0);
  if (i0 + 3 < N) {
    v = *(const int4*)(deg + i0);
  } else {
    if (i0 < N) v.x = deg[i0];
    if (i0 + 1 < N) v.y = deg[i0 + 1];
    if (i0 + 2 < N) v.z = deg[i0 + 2];
  }
  int s = v.x + v.y + v.z + v.w;
#pragma unroll
  for (int m = 32; m; m >>= 1) s += __shfl_xor(s, m);
  if (lane == 0) wsum[w] = s;
  __syncthreads();
  if (tid == 0) partial[blockIdx.x] = wsum[0] + wsum[1] + wsum[2] + wsum[3];
}

// ---- scan part 2: exclusive scan of chunk partials (<=128 chunks fast path) ----
__global__ void k_scanroot(int* __restrict__ partial, int* __restrict__ offsets,
                           int NB, int N) {
  if (NB <= 128) {
    int lane = threadIdx.x;
    int a = (lane < NB) ? partial[lane] : 0;
    int b = (lane + 64 < NB) ? partial[lane + 64] : 0;
    int sa = a, sb = b;
#pragma unroll
    for (int off = 1; off < 64; off <<= 1) {
      int t = __shfl_up(sa, off);
      if (lane >= off) sa += t;
      int u = __shfl_up(sb, off);
      if (lane >= off) sb += u;
    }
    int atot = __shfl(sa, 63);
    sb += atot;
    int tot = __shfl(sb, 63);
    if (lane < NB) partial[lane] = sa - a;
    if (lane + 64 < NB) partial[lane + 64] = sb - b;
    if (lane == 0) offsets[N] = tot;
  } else {
    if (threadIdx.x == 0) {
      int run = 0;
      for (int bI = 0; bI < NB; ++bI) {
        int vv = partial[bI];
        partial[bI] = run;
        run += vv;
      }
      offsets[N] = run;
    }
  }
}

// ---- scan part 3: local exclusive scan + base -> offsets & cursor ----
__global__ void k_scanapply(const int* __restrict__ deg, const int* __restrict__ partial,
                            int* __restrict__ offsets, int* __restrict__ cursor, int N) {
  __shared__ int wsum[4];
  int tid = threadIdx.x, lane = tid & 63, w = tid >> 6;
  int i0 = blockIdx.x * 1024 + tid * 4;
  int4 v = make_int4(0, 0, 0, 0);
  if (i0 + 3 < N) {
    v = *(const int4*)(deg + i0);
  } else {
    if (i0 < N) v.x = deg[i0];
    if (i0 + 1 < N) v.y = deg[i0 + 1];
    if (i0 + 2 < N) v.z = deg[i0 + 2];
  }
  int ts = v.x + v.y + v.z + v.w;
  int s = ts;
#pragma unroll
  for (int off = 1; off < 64; off <<= 1) {
    int t = __shfl_up(s, off);
    if (lane >= off) s += t;
  }
  if (lane == 63) wsum[w] = s;
  __syncthreads();
  int wb = 0;
#pragma unroll
  for (int x = 0; x < 4; ++x)
    if (x < w) wb += wsum[x];
  int excl = s - ts + wb + partial[blockIdx.x];
  int o0 = excl, o1 = o0 + v.x, o2 = o1 + v.y, o3 = o2 + v.z;
  if (i0 + 3 < N) {
    int4 o = make_int4(o0, o1, o2, o3);
    *(int4*)(offsets + i0) = o;
    *(int4*)(cursor + i0) = o;
  } else {
    if (i0 < N) { offsets[i0] = o0; cursor[i0] = o0; }
    if (i0 + 1 < N) { offsets[i0 + 1] = o1; cursor[i0 + 1] = o1; }
    if (i0 + 2 < N) { offsets[i0 + 2] = o2; cursor[i0 + 2] = o2; }
  }
}

// ---- scatter edges into CSR (packed int2: src node, edge id) ----
__global__ void k_scatter(const int* __restrict__ src, const int* __restrict__ dstA,
                          int* __restrict__ cursor, int2* __restrict__ je, int E) {
  int e = blockIdx.x * blockDim.x + threadIdx.x;
  if (e >= E) return;
  int d = dstA[e];
  int p = atomicAdd(&cursor[d], 1);
  je[p] = make_int2(src[e], e);
}

__device__ __forceinline__ float bcastf(float v, int srclane) {
  return __int_as_float(__builtin_amdgcn_readlane(__float_as_int(v), srclane));
}

// ---- node linear: outa = hin@Wa + ba ; outb = hin@Wb + bb (stride-able) ----
__global__ __launch_bounds__(256, 1) void k_nodelin(
    const float* __restrict__ hin, const float* __restrict__ Wa,
    const float* __restrict__ ba, const float* __restrict__ Wb,
    const float* __restrict__ bb, float* __restrict__ outa, float* __restrict__ outb,
    int ostride, int N) {
  int lane = threadIdx.x & 63;
  int wave = blockIdx.x * (blockDim.x >> 6) + (threadIdx.x >> 6);
  int nwaves = gridDim.x * (blockDim.x >> 6);
  float wa[64], wb[64];
#pragma unroll
  for (int c = 0; c < 64; ++c) {
    wa[c] = Wa[c * 64 + lane];
    wb[c] = Wb[c * 64 + lane];
  }
  float bav = ba[lane], bbv = bb[lane];
  for (int i = wave; i < N; i += nwaves) {
    float h = hin[(size_t)i * 64 + lane];
    float a = bav, b = bbv;
#pragma unroll
    for (int c = 0; c < 64; ++c) {
      float hc = bcastf(h, c);
      a = fmaf(hc, wa[c], a);
      b = fmaf(hc, wb[c], b);
    }
    outa[(size_t)i * ostride + lane] = a;
    outb[(size_t)i * ostride + lane] = b;
  }
}

// ---- edge gather + gate + aggregate + skip + elu (+ output fusion) ----
// qv layout: row i = [q_i (64) | v_i (64)], stride 128.
#define EDGE_LOAD(K, T)                                                        \
  int j##K = __builtin_amdgcn_readlane(meta.x, (T));                           \
  int eI##K = __builtin_amdgcn_readlane(meta.y, (T));                          \
  const float4* ap##K = (const float4*)(ea + (size_t)eI##K * E_CH);            \
  float4 eA##K##a = ap##K[0], eA##K##b = ap##K[1], eA##K##c = ap##K[2],        \
         eA##K##d = ap##K[3];                                                  \
  float q##K = qv[(size_t)j##K * 128 + lane];                                  \
  float v##K = qv[(size_t)j##K * 128 + 64 + lane];

#define EDGE_COMP(K)                                                           \
  {                                                                            \
    float ev = 0.f;                                                            \
    ev = fmaf(eA##K##a.x, we[0], ev);                                          \
    ev = fmaf(eA##K##a.y, we[1], ev);                                          \
    ev = fmaf(eA##K##a.z, we[2], ev);                                          \
    ev = fmaf(eA##K##a.w, we[3], ev);                                          \
    ev = fmaf(eA##K##b.x, we[4], ev);                                          \
    ev = fmaf(eA##K##b.y, we[5], ev);                                          \
    ev = fmaf(eA##K##b.z, we[6], ev);                                          \
    ev = fmaf(eA##K##b.w, we[7], ev);                                          \
    ev = fmaf(eA##K##c.x, we[8], ev);                                          \
    ev = fmaf(eA##K##c.y, we[9], ev);                                          \
    ev = fmaf(eA##K##c.z, we[10], ev);                                         \
    ev = fmaf(eA##K##c.w, we[11], ev);                                         \
    ev = fmaf(eA##K##d.x, we[12], ev);                                         \
    ev = fmaf(eA##K##d.y, we[13], ev);                                         \
    ev = fmaf(eA##K##d.z, we[14], ev);                                         \
    ev = fmaf(eA##K##d.w, we[15], ev);                                         \
    float g = ki + q##K + ev;                                                  \
    g = 1.0f / (1.0f + __expf(-g));                                            \
    acc = fmaf(g, v##K, acc);                                                  \
  }

template <int MODE>
__global__ __launch_bounds__(256, 3) void k_edge(
    const int* __restrict__ offsets, const int2* __restrict__ je,
    const float* __restrict__ kk, const float* __restrict__ qv,
    const float* __restrict__ base, const float* __restrict__ ea,
    const float* __restrict__ We, const float* __restrict__ be,
    float* __restrict__ hnext, float* __restrict__ dout,
    const float* __restrict__ Wl, const float* __restrict__ bl, int N) {
  int lane = threadIdx.x & 63;
  int wave = blockIdx.x * (blockDim.x >> 6) + (threadIdx.x >> 6);
  int nwaves = gridDim.x * (blockDim.x >> 6);
  float we[16];
#pragma unroll
  for (int c = 0; c < 16; ++c) we[c] = We[c * 64 + lane];
  float bev = be[lane];
  float wl = (MODE == 2) ? Wl[lane] : 0.f;
  float bl0 = (MODE == 2) ? bl[0] : 0.f;
  for (int i = wave; i < N; i += nwaves) {
    float ki = kk[(size_t)i * 64 + lane] + bev;  // fold be into k_i
    float acc = base[(size_t)i * 64 + lane];
    int p0 = __builtin_amdgcn_readfirstlane(offsets[i]);
    int p1 = __builtin_amdgcn_readfirstlane(offsets[i + 1]);
    for (int pb = p0; pb < p1; pb += 64) {
      int m = p1 - pb;
      if (m > 64) m = 64;
      // cooperative CSR metadata load: one coalesced int2 per lane covers 64 edges
      int idx = pb + ((lane < m) ? lane : 0);
      int2 meta = je[idx];
      int t = 0;
      for (; t + 4 <= m; t += 4) {
        EDGE_LOAD(0, t)
        EDGE_LOAD(1, t + 1)
        EDGE_LOAD(2, t + 2)
        EDGE_LOAD(3, t + 3)
        EDGE_COMP(0)
        EDGE_COMP(1)
        EDGE_COMP(2)
        EDGE_COMP(3)
      }
      for (; t < m; ++t) {
        EDGE_LOAD(5, t)
        EDGE_COMP(5)
      }
    }
    float r = (acc > 0.f) ? acc : expm1f(acc);  // elu
    if (MODE == 0) {
      hnext[(size_t)i * 64 + lane] = r;
    } else if (MODE == 1) {
      hnext[(size_t)i * 64 + lane] = r;
      dout[(size_t)N + (size_t)i * 64 + lane] = r;       // feat block
      dout[(size_t)N * 65 + (size_t)i * 65 + lane] = r;  // concat block
    } else {
      float dot = r * wl;
#pragma unroll
      for (int m2 = 32; m2 >= 1; m2 >>= 1) dot += __shfl_xor(dot, m2);
      float logit = dot + bl0;
      if (lane == 0) {
        dout[i] = 1.0f / (1.0f + __expf(-logit));
        dout[(size_t)N * 65 + (size_t)i * 65 + 64] = logit;  // raw logit col
      }
    }
  }
}

extern "C" void kernel_launch(void* const* d_in, const int* in_sizes, int n_in,
                              void* d_out, int out_size, void* d_ws, size_t ws_size,
                              hipStream_t stream) {
  const float* x   = (const float*)d_in[0];
  const void*  ei  = d_in[1];
  const float* ea  = (const float*)d_in[2];
  const float* Wk  = (const float*)d_in[3];
  const float* bk  = (const float*)d_in[4];
  const float* Wq  = (const float*)d_in[5];
  const float* bq  = (const float*)d_in[6];
  const float* Wv  = (const float*)d_in[7];
  const float* bv  = (const float*)d_in[8];
  const float* We  = (const float*)d_in[9];
  const float* be  = (const float*)d_in[10];
  const float* Ws  = (const float*)d_in[11];
  const float* bia = (const float*)d_in[12];
  const float* Wl  = (const float*)d_in[13];
  const float* bl  = (const float*)d_in[14];
  int N = in_sizes[0] / D_CH;
  int E = in_sizes[2] / E_CH;
  int NB = (N + 1023) / 1024;

  char* w = (char*)d_ws;
  auto alloc = [&](size_t bytes) -> char* {
    char* r = w;
    w += (bytes + 255) & ~(size_t)255;
    return r;
  };
  int* flag     = (int*)alloc(16);
  int* src      = (int*)alloc((size_t)E * 4);
  int* dstA     = (int*)alloc((size_t)E * 4);
  int* deg      = (int*)alloc((size_t)N * 4);
  int* partial  = (int*)alloc((size_t)NB * 4);
  int* offsets  = (int*)alloc((size_t)(N + 1) * 4);
  int* cursor   = (int*)alloc((size_t)N * 4);
  int2* je      = (int2*)alloc((size_t)E * 8);
  float* kk     = (float*)alloc((size_t)N * D_CH * 4);
  float* qv     = (float*)alloc((size_t)N * 128 * 4);
  float* baseb  = (float*)alloc((size_t)N * D_CH * 4);
  float* h1     = (float*)alloc((size_t)N * D_CH * 4);
  float* feat   = (float*)alloc((size_t)N * D_CH * 4);
  float* dout   = (float*)d_out;

  int gE = (E + 255) / 256;
  int gN = (N + 255) / 256;

  k_prep<<<gN, 256, 0, stream>>>((const unsigned int*)ei, flag, deg, N, 8192);
  k_normhist<<<gE, 256, 0, stream>>>(ei, flag, src, dstA, deg, E);
  k_scanpart<<<NB, 256, 0, stream>>>(deg, partial, N);
  k_scanroot<<<1, 64, 0, stream>>>(partial, offsets, NB, N);
  k_scanapply<<<NB, 256, 0, stream>>>(deg, partial, offsets, cursor, N);
  k_scatter<<<gE, 256, 0, stream>>>(src, dstA, cursor, je, E);

  const float* hin = x;
  for (int l = 0; l < 3; ++l) {
    const float* Wk_l = Wk + (size_t)l * 4096;
    const float* bk_l = bk + (size_t)l * 64;
    const float* Wq_l = Wq + (size_t)l * 4096;
    const float* bq_l = bq + (size_t)l * 64;
    const float* Wv_l = Wv + (size_t)l * 4096;
    const float* bv_l = bv + (size_t)l * 64;
    const float* We_l = We + (size_t)l * 1024;
    const float* be_l = be + (size_t)l * 64;
    const float* Ws_l = Ws + (size_t)l * 4096;
    const float* bi_l = bia + (size_t)l * 64;

    // k and skip-base (stride 64); q and v interleaved into qv (stride 128)
    k_nodelin<<<1024, 256, 0, stream>>>(hin, Wk_l, bk_l, Ws_l, bi_l, kk, baseb, 64, N);
    k_nodelin<<<1024, 256, 0, stream>>>(hin, Wq_l, bq_l, Wv_l, bv_l, qv, qv + 64, 128, N);
    if (l == 0) {
      k_edge<0><<<2048, 256, 0, stream>>>(offsets, je, kk, qv, baseb, ea, We_l, be_l,
                                          h1, dout, Wl, bl, N);
      hin = h1;
    } else if (l == 1) {
      k_edge<1><<<2048, 256, 0, stream>>>(offsets, je, kk, qv, baseb, ea, We_l, be_l,
                                          feat, dout, Wl, bl, N);
      hin = feat;
    } else {
      k_edge<2><<<2048, 256, 0, stream>>>(offsets, je, kk, qv, baseb, ea, We_l, be_l,
                                          h1, dout, Wl, bl, N);
    }
  }
}